// Round 3
// baseline (65240.021 us; speedup 1.0000x reference)
//
#include <hip/hip_runtime.h>
#include <hip/hip_bf16.h>
#include <hip/hip_fp16.h>
#include <math.h>

// ---------------------------------------------------------------------------
// OfficialXLSTMModel: B=4, S=2048, D=1024, L=4, H=4, DH=256, K=4, UP=1344
// Input dtype (fp32 vs bf16) detected AT RUNTIME from ln1_w's bit pattern.
// Internal compute fp32; residual X fp32; canonical activations bf16.
// Workspace: exactly 128 MiB.
// R7: enforce weight residency in k_recur. R6 counters showed VGPR_Count=64:
//     the compiler sank the wreg[64] "resident" loads back into the step loop
//     (occupancy heuristic targeted the 64-VGPR bin, ignoring that 101.5KB
//     LDS already caps us at 1 block/CU = 4 waves/SIMD). Every step re-issued
//     ~64 global_load_dword per thread -> repeated L2 latency rounds.
//     Fix: __launch_bounds__(1024,4) raises the VGPR budget to 128, and an
//     asm "+v" keep-alive per wreg element blocks load rematerialization.
// R5: k_recur restructured for latency hiding: 1024 thr, thread=(gate,cell),
//     4 waves/SIMD TLP. Weights: 64 f16-pairs in VGPR, 24 pairs in 96KB LDS,
//     40 pairs L2-streamed (10 coalesced uint4/step). Gate combine via araw[]
//     LDS; update+GN on first 4 waves; X+= after barrier 2.
// ---------------------------------------------------------------------------

typedef unsigned int  u32;
typedef unsigned short u16;
typedef __hip_bfloat16 bf16;

typedef short bf16x8 __attribute__((ext_vector_type(8)));   // 8 bf16 MFMA A/B frag
typedef float f32x4  __attribute__((ext_vector_type(4)));   // MFMA C/D frag
typedef _Float16 half2t __attribute__((ext_vector_type(2)));

#define EPSF 1e-5f
#define SIGF32 0x3F800000u

// ---- helpers --------------------------------------------------------------
__device__ __forceinline__ float bfu2f(u16 u){ return __uint_as_float(((u32)u) << 16); }
__device__ __forceinline__ float ldm(const void* p, long i, int f32){
  return f32 ? ((const float*)p)[i] : bfu2f(((const u16*)p)[i]);
}
// f16-pair (packed u32) * two f32 h-values, fp32 accumulate (v_fma_mix).
__device__ __forceinline__ float pairacc(u32 w, float h0, float h1, float acc){
  half2t a = __builtin_bit_cast(half2t, w);
  acc = fmaf((float)a.x, h0, acc);
  acc = fmaf((float)a.y, h1, acc);
  return acc;
}

// ---- canary: signal environmental mismatch through absmax -----------------
__global__ __launch_bounds__(256) void k_canary(const u32* __restrict__ sig,
                                                void* __restrict__ out, int n, float code){
  int f32 = (sig[0] == SIGF32);
  int i = blockIdx.x*256 + threadIdx.x;
  if (i >= n) return;
  float v = (i == 0) ? code : 0.f;
  if (f32) ((float*)out)[i] = v;
  else     ((bf16*)out)[i]  = __float2bfloat16(v);
}

// ---- cast x -> residual X fp32 --------------------------------------------
__global__ __launch_bounds__(256) void k_cast(const void* __restrict__ in,
                                              const u32* __restrict__ sig,
                                              float* __restrict__ out){
  int f32 = (sig[0] == SIGF32);
  long i = (long)blockIdx.x*256 + threadIdx.x;    // < 2097152 (x4 elements)
  if (f32){
    ((float4*)out)[i] = ((const float4*)in)[i];
  } else {
    ushort4 v = ((const ushort4*)in)[i];
    float4 f;
    f.x = bfu2f(v.x); f.y = bfu2f(v.y); f.z = bfu2f(v.z); f.w = bfu2f(v.w);
    ((float4*)out)[i] = f;
  }
}

// ---- generic elementwise convert -> canonical bf16 ------------------------
__global__ __launch_bounds__(256) void k_cvt(const void* __restrict__ src, long off,
                                             const u32* __restrict__ sig,
                                             bf16* __restrict__ dst, int n){
  int f32 = (sig[0] == SIGF32);
  int i = blockIdx.x*256 + threadIdx.x;
  if (i < n) dst[i] = __float2bfloat16(ldm(src, off + i, f32));
}

// ---- LayerNorm over D=1024, fp32 in -> bf16 (or dtype-matched final) out --
__global__ __launch_bounds__(256) void k_ln(const float* __restrict__ X,
                                            const void* __restrict__ w, long woff,
                                            const u32* __restrict__ sig,
                                            void* __restrict__ out, int outf){
  int f32 = (sig[0] == SIGF32);
  int row = blockIdx.x, t = threadIdx.x;
  float4 xv = ((const float4*)(X + (long)row*1024))[t];
  float s1 = xv.x + xv.y + xv.z + xv.w;
  float s2 = xv.x*xv.x + xv.y*xv.y + xv.z*xv.z + xv.w*xv.w;
  #pragma unroll
  for (int off = 32; off >= 1; off >>= 1){ s1 += __shfl_xor(s1, off); s2 += __shfl_xor(s2, off); }
  __shared__ float rb[8];
  if ((t & 63) == 0){ rb[t>>6] = s1; rb[4 + (t>>6)] = s2; }
  __syncthreads();
  s1 = rb[0]+rb[1]+rb[2]+rb[3];
  s2 = rb[4]+rb[5]+rb[6]+rb[7];
  float mu  = s1 * (1.f/1024.f);
  float var = s2 * (1.f/1024.f) - mu*mu;
  float rs  = rsqrtf(fmaxf(var, 0.f) + EPSF);
  float xs[4] = {xv.x, xv.y, xv.z, xv.w};
  #pragma unroll
  for (int j = 0; j < 4; j++){
    float val = (xs[j]-mu)*rs*ldm(w, woff + t*4 + j, f32);
    long oi = (long)row*1024 + t*4 + j;
    if (outf && f32) ((float*)out)[oi] = val;
    else             ((bf16*)out)[oi]  = __float2bfloat16(val);
  }
}

// ---- causal depthwise conv (K=4) + SiLU: XN -> WX z/o column region -------
__global__ __launch_bounds__(256) void k_conv(const bf16* __restrict__ XN,
                                              const void* __restrict__ cw, long cwoff,
                                              const void* __restrict__ cb, long cboff,
                                              const u32* __restrict__ sig,
                                              bf16* __restrict__ WX){
  int f32 = (sig[0] == SIGF32);
  int idx = blockIdx.x*256 + threadIdx.x;        // < 8388608
  int c = idx & 1023;
  int s = (idx >> 10) & 2047;
  int b = idx >> 21;
  float acc = ldm(cb, cboff + c, f32);
  const bf16* xp = XN + idx;
  #pragma unroll
  for (int k = 0; k < 4; k++){
    int sk = s - 3 + k;
    float xv = (sk >= 0) ? (float)xp[(k-3)*1024] : 0.f;
    acc += xv * ldm(cw, cwoff + c*4 + k, f32);
  }
  float sg = 1.f / (1.f + __expf(-acc));
  WX[(long)b*8388608 + (long)(c>>8)*2097152 + (long)s*1024 + 512 + (c & 255)]
      = __float2bfloat16(acc * sg);
}

// ---- pack rker into f16 pairs, three regions ------------------------------
// pair dp in [0,128) covers d = 2dp, 2dp+1.  gc = g*256 + cell (= WX column).
// dp in [0,64):   rkReg[(dp*4 + h)*1024 + gc]                    (VGPR-resident)
// dp in [64,88):  rkLds u32 [(h*6 + k)*1024 + gc]*4 + j, k=(dp-64)>>2, j=(dp-64)&3  (LDS)
// dp in [88,128): rkStr u32 [(h*10 + pg)*1024 + gc]*4 + j, pg=(dp-88)>>2, j=(dp-88)&3 (L2 stream)
__global__ __launch_bounds__(256) void k_packrk(const void* __restrict__ rk, long off,
                                                const u32* __restrict__ sig,
                                                u32* __restrict__ rkReg,
                                                u32* __restrict__ rkLds,
                                                u32* __restrict__ rkStr){
  int f32 = (sig[0] == SIGF32);
  int idx = blockIdx.x*256 + threadIdx.x;        // < 4*1024*128
  if (idx >= 524288) return;
  int dp = idx & 127;
  int gc = (idx >> 7) & 1023;                    // gc = g*256 + cell
  int h  = idx >> 17;
  long p = off + (long)h*262144 + (long)(dp*2)*1024 + gc;
  float a = ldm(rk, p, f32);
  float b = ldm(rk, p + 1024, f32);
  u32 lo = (u32)__builtin_bit_cast(u16, (_Float16)a);
  u32 hi = (u32)__builtin_bit_cast(u16, (_Float16)b);
  u32 v = lo | (hi << 16);
  if (dp < 64){
    rkReg[((long)dp*4 + h)*1024 + gc] = v;
  } else if (dp < 88){
    int k = (dp-64)>>2, j = (dp-64)&3;
    rkLds[((long)(h*6 + k)*1024 + gc)*4 + j] = v;
  } else {
    int pg = (dp-88)>>2, j = (dp-88)&3;
    rkStr[((long)(h*10 + pg)*1024 + gc)*4 + j] = v;
  }
}

// ---- tiled transpose: in[R][C] (fp32/bf16) -> out[C][R] bf16 --------------
__global__ __launch_bounds__(256) void k_transpose(const void* __restrict__ in, long off,
                                                   const u32* __restrict__ sig,
                                                   bf16* __restrict__ out, int R, int C){
  int f32 = (sig[0] == SIGF32);
  __shared__ bf16 tile[32][33];
  int tx = threadIdx.x & 31, ty = threadIdx.x >> 5;
  int r0 = blockIdx.y*32, c0 = blockIdx.x*32;
  #pragma unroll
  for (int i = 0; i < 4; i++)
    tile[ty + i*8][tx] = __float2bfloat16(ldm(in, off + (long)(r0 + ty + i*8)*C + c0 + tx, f32));
  __syncthreads();
  #pragma unroll
  for (int i = 0; i < 4; i++) out[(long)(c0 + ty + i*8)*R + r0 + tx] = tile[tx][ty + i*8];
}

// ---- bf16 MFMA GEMM, 128x128 tile, direct global loads --------------------
__global__ __launch_bounds__(256) void k_gemm(const bf16* __restrict__ A, int lda, int aoff, int agate,
                                              const bf16* __restrict__ B0,
                                              const bf16* __restrict__ B1, int ldb, int nsplit,
                                              int K, int mode,
                                              bf16* __restrict__ outb, int ldo, int woff,
                                              float* __restrict__ resid){
  int lane = threadIdx.x & 63, wv = threadIdx.x >> 6;
  int wrow = wv >> 1, wcol = wv & 1;
  int m15 = lane & 15, q = lane >> 4;
  int mBase = blockIdx.x*128 + wrow*64;
  int nBase = blockIdx.y*128 + wcol*64;

  const bf16* Ap[4]; const bf16* Bp[4];
  #pragma unroll
  for (int i = 0; i < 4; i++){
    int row = mBase + i*16 + m15;
    long abase = agate ? ((long)(row >> 11)*8388608 + (long)(row & 2047)*1024)
                       : ((long)row*lda);
    Ap[i] = A + abase + aoff + q*8;
    int n = nBase + i*16 + m15;
    const bf16* bb = (n < nsplit) ? (B0 + (long)n*ldb) : (B1 + (long)(n - nsplit)*ldb);
    Bp[i] = bb + q*8;
  }
  f32x4 acc[4][4];
  f32x4 zero = {0.f, 0.f, 0.f, 0.f};
  #pragma unroll
  for (int i = 0; i < 4; i++)
    #pragma unroll
    for (int j = 0; j < 4; j++) acc[i][j] = zero;

  for (int k0 = 0; k0 < K; k0 += 32){
    bf16x8 af[4], bfg[4];
    #pragma unroll
    for (int i = 0; i < 4; i++){ af[i]  = *reinterpret_cast<const bf16x8*>(Ap[i]); Ap[i] += 32; }
    #pragma unroll
    for (int i = 0; i < 4; i++){ bfg[i] = *reinterpret_cast<const bf16x8*>(Bp[i]); Bp[i] += 32; }
    #pragma unroll
    for (int i = 0; i < 4; i++)
      #pragma unroll
      for (int j = 0; j < 4; j++)
        acc[i][j] = __builtin_amdgcn_mfma_f32_16x16x32_bf16(af[i], bfg[j], acc[i][j], 0, 0, 0);
  }

  #pragma unroll
  for (int i = 0; i < 4; i++){
    #pragma unroll
    for (int j = 0; j < 4; j++){
      #pragma unroll
      for (int r = 0; r < 4; r++){
        int row = mBase + i*16 + q*4 + r;       // C/D layout: col=lane&15, row=quad*4+reg
        int col = nBase + j*16 + m15;
        float v = acc[i][j][r];
        if (mode == 0){
          outb[(long)row*ldo + col] = __float2bfloat16(v);
        } else if (mode == 1){
          outb[(long)(row >> 11)*8388608 + (long)(row & 2047)*1024 + woff + col] = __float2bfloat16(v);
        } else {
          resid[(long)row*1024 + col] += v;
        }
      }
    }
  }
}

// ---- GEGLU activation: U[8192][2688] -> E[8192][1344] ---------------------
__global__ __launch_bounds__(256) void k_act(const bf16* __restrict__ U, bf16* __restrict__ E){
  int idx = blockIdx.x*256 + threadIdx.x;        // < 8192*1344
  int row = idx / 1344;
  int j   = idx - row*1344;
  float g = (float)U[(long)row*2688 + j];
  float v = (float)U[(long)row*2688 + 1344 + j];
  float ge = 0.5f * g * (1.f + erff(g * 0.70710678118654752f));
  E[idx] = __float2bfloat16(ge * v);
}

// ---- sLSTM recurrence + fused GroupNorm + residual add --------------------
// 16 workgroups = (b,h); 1024 threads; thread tid = (gate g = tid>>8, cell = tid&255).
// Per step: every thread computes one gate pre-activation (256-dot against h),
// writes araw[tid]; first 4 waves do the cell update + GroupNorm; X-residual
// RMW deferred past barrier 2 so it overlaps the next step's dot phase.
// __launch_bounds__(1024, 4): 4 waves/EU (what LDS=101.5KB forces anyway) ->
// VGPR budget 128, so wreg[64] can stay resident. asm "+v" keep-alives make
// each wreg element an asm-defined value, blocking load rematerialization.
__global__ __launch_bounds__(1024, 4) void k_recur(const bf16* __restrict__ WX,  // [16][2048][1024]
                                                const u32*  __restrict__ rkReg,  // [64 dp][4 h][1024 gc]
                                                const uint4* __restrict__ rkLdsG,// [4 h][6 k][1024 gc]
                                                const uint4* __restrict__ rkStrG,// [4 h][10 pg][1024 gc]
                                                const void* __restrict__ cb, long cboff,
                                                const void* __restrict__ gnw, long gnoff,
                                                const u32*  __restrict__ sig,
                                                float* __restrict__ X,
                                                int szero){
  int f32 = (sig[0] == SIGF32);
  int bh = blockIdx.x;
  int b = bh >> 2, h = bh & 3;
  int tid = threadIdx.x;
  int cell = tid & 255;

  // resident weights: 64 f16-pairs (d = 0..127) = 64 VGPRs
  u32 wreg[64];
  {
    const u32* rg = rkReg + h*1024 + tid;
    #pragma unroll
    for (int i = 0; i < 64; i++) wreg[i] = rg[i*4096];
  }
  // Pin in VGPRs: asm "writes" each value, so the loads above cannot be
  // sunk/rematerialized inside the step loop (R6 pathology: VGPR_Count=64).
  #pragma unroll
  for (int i = 0; i < 64; i++) asm volatile("" : "+v"(wreg[i]));

  __shared__ __align__(16) uint4 wlds[6144];     // 96 KB: pairs d=128..175, [k][tid]
  __shared__ __align__(16) float araw[1024];     // raw gate pre-activations
  __shared__ __align__(16) float hs[256];        // h state (broadcast operand)
  __shared__ float rbuf[8];
  {
    const uint4* srcL = rkLdsG + h*6144;
    #pragma unroll
    for (int k = 0; k < 6; k++) wlds[k*1024 + tid] = srcL[k*1024 + tid];
  }

  // L2-stream base: pairs d=176..255, 10 coalesced uint4 per thread per step
  const uint4* st = rkStrG + h*10240 + tid;

  float bias = ldm(cb, cboff + h*1024 + tid, f32);
  float gw   = ldm(gnw, gnoff + h*256 + cell, f32);

  if (tid < 256) hs[tid] = 0.f;
  __syncthreads();

  float c = 0.f, n = 0.f, m = 0.f;               // live in first 4 waves only
  const u16* wxu = (const u16*)(WX + (long)bh*2097152) + tid;
  float* Xp = X + (long)b*2097152 + h*256 + cell;

  u16 wxc = wxu[0];
  for (int s = 0; s < 2048; s++){
    u16 wxn = wxu[(s < 2047) ? 1024 : 0];        // prefetch next step's input
    int off = s * szero;                         // runtime 0: defeats LICM on
    const float4* hv4 = (const float4*)hs;       // LDS + L2 weight loads

    float acc = bias + bfu2f(wxc);
    #pragma unroll
    for (int i = 0; i < 16; i++){                // pairs 0..31 (VGPR)
      float4 hv = hv4[i];
      acc = pairacc(wreg[2*i],   hv.x, hv.y, acc);
      acc = pairacc(wreg[2*i+1], hv.z, hv.w, acc);
    }
    #pragma unroll
    for (int i = 16; i < 32; i++){               // pairs 32..63 (VGPR)
      float4 hv = hv4[i];
      acc = pairacc(wreg[2*i],   hv.x, hv.y, acc);
      acc = pairacc(wreg[2*i+1], hv.z, hv.w, acc);
    }
    #pragma unroll
    for (int k = 0; k < 6; k++){                 // pairs 64..87 (LDS)
      uint4 q = wlds[k*1024 + tid + off];
      float4 ha = hv4[32+2*k], hb = hv4[33+2*k];
      acc = pairacc(q.x, ha.x, ha.y, acc); acc = pairacc(q.y, ha.z, ha.w, acc);
      acc = pairacc(q.z, hb.x, hb.y, acc); acc = pairacc(q.w, hb.z, hb.w, acc);
    }
    #pragma unroll
    for (int pg = 0; pg < 10; pg++){             // pairs 88..127 (L2 stream)
      uint4 q = st[pg*1024 + off];
      float4 ha = hv4[44+2*pg], hb = hv4[45+2*pg];
      acc = pairacc(q.x, ha.x, ha.y, acc); acc = pairacc(q.y, ha.z, ha.w, acc);
      acc = pairacc(q.z, hb.x, hb.y, acc); acc = pairacc(q.w, hb.z, hb.w, acc);
    }
    araw[tid] = acc;
    __syncthreads();                             // B1: araw ready; old hs consumed

    float y = 0.f;
    if (tid < 256){
      float a0 = araw[cell], a1 = araw[256+cell], a2 = araw[512+cell], a3 = araw[768+cell];
      float lsig = fminf(a1, 0.f) - log1pf(__expf(-fabsf(a1)));
      float lfm  = m + lsig;
      float mn   = fmaxf(a0, lfm);
      float ig   = __expf(a0 - mn);
      float fg   = __expf(lfm - mn);
      float cn   = fg*c + ig*tanhf(a2);
      float nn   = fg*n + ig;
      float hn   = (1.f/(1.f + __expf(-a3))) * cn / nn;
      c = cn; n = nn; m = mn;
      hs[cell] = hn;                             // safe: old hs dead past B1
      float r1 = hn, r2 = hn*hn;
      #pragma unroll
      for (int o2 = 32; o2 >= 1; o2 >>= 1){ r1 += __shfl_xor(r1, o2); r2 += __shfl_xor(r2, o2); }
      if ((tid & 63) == 0){ rbuf[tid>>6] = r1; rbuf[4 + (tid>>6)] = r2; }
      y = hn;
    }
    __syncthreads();                             // B2: hs + rbuf ready

    if (tid < 256){                              // GN + residual overlap next dots
      float S1 = rbuf[0]+rbuf[1]+rbuf[2]+rbuf[3];
      float S2 = rbuf[4]+rbuf[5]+rbuf[6]+rbuf[7];
      float mu  = S1 * (1.f/256.f);
      float var = S2 * (1.f/256.f) - mu*mu;
      *Xp += (y - mu) * rsqrtf(fmaxf(var, 0.f) + EPSF) * gw;
    }
    Xp += 1024;
    wxu += 1024;
    wxc = wxn;
  }
}

// ---------------------------------------------------------------------------
extern "C" void kernel_launch(void* const* d_in, const int* in_sizes, int n_in,
                              void* d_out, int out_size, void* d_ws, size_t ws_size,
                              hipStream_t stream){
  const void* x_in   = d_in[0];
  const void* ln1_w  = d_in[1];
  const void* conv_w = d_in[2];
  const void* conv_b = d_in[3];
  const void* wi     = d_in[4];
  const void* wf     = d_in[5];
  const void* wz     = d_in[6];
  const void* wo     = d_in[7];
  const void* rker   = d_in[8];
  const void* cell_b = d_in[9];
  const void* gn_w   = d_in[10];
  const void* ln2_w  = d_in[11];
  const void* ff_up  = d_in[12];
  const void* ff_dn  = d_in[13];
  const void* post_w = d_in[14];
  const u32* sig = (const u32*)ln1_w;

  if (ws_size < 134217728ULL){
    k_canary<<<(out_size+255)/256, 256, 0, stream>>>(sig, d_out, out_size, 4000.f);
    return;
  }
  if (n_in < 15 || in_sizes[0] != 8388608 || in_sizes[8] != 4194304 ||
      in_sizes[12] != 11010048 || out_size != 8388608){
    k_canary<<<(out_size+255)/256, 256, 0, stream>>>(sig, d_out, out_size, 8000.f);
    return;
  }

  char* ws = (char*)d_ws;
  // layout (exactly 128 MiB):
  //   [0,32M)    X    fp32 residual
  //   [32,48M)   XN   bf16 LN output
  //   [48,64M)   scratch: rkReg 1M | rkLds 384K | rkStr 640K | gW 2M | fupT 5.25M | fdnT 2.63M
  //   [64,128M)  WX bf16 [4 b][4 h][2048 s][1024]; conv output lives in its
  //              z/o cols until side-1 gemms; U(44M)+E(21M) alias it in FFN.
  float* X    = (float*)(ws + 0);
  bf16*  XN   = (bf16*) (ws + 33554432);
  u32*   rkReg= (u32*)  (ws + 50331648);
  u32*   rkLds= (u32*)  (ws + 50331648 + 1048576);
  u32*   rkStr= (u32*)  (ws + 50331648 + 1441792);
  bf16*  gW   = (bf16*) (ws + 50331648 + 2097152);
  bf16*  fupT = (bf16*) (ws + 50331648 + 4194304);
  bf16*  fdnT = (bf16*) (ws + 50331648 + 9699328);
  bf16*  WX   = (bf16*) (ws + 67108864);
  bf16*  U    = WX;
  bf16*  E    = (bf16*) (ws + 67108864 + 44040192);

  k_cast<<<8192, 256, 0, stream>>>(x_in, sig, X);

  for (int l = 0; l < 4; l++){
    k_ln<<<8192, 256, 0, stream>>>(X, ln1_w, (long)l*1024, sig, XN, 0);
    k_conv<<<32768, 256, 0, stream>>>(XN, conv_w, (long)l*4096, conv_b, (long)l*1024, sig, WX);

    // canonical bf16 gate weights for this layer
    k_cvt<<<1024, 256, 0, stream>>>(wi, (long)l*262144, sig, gW +      0, 262144);
    k_cvt<<<1024, 256, 0, stream>>>(wf, (long)l*262144, sig, gW + 262144, 262144);
    k_cvt<<<1024, 256, 0, stream>>>(wz, (long)l*262144, sig, gW + 524288, 262144);
    k_cvt<<<1024, 256, 0, stream>>>(wo, (long)l*262144, sig, gW + 786432, 262144);

    for (int h = 0; h < 4; h++){
      // gates i,f: A = conv output (in WX z/o cols), writes i/f cols
      k_gemm<<<dim3(64,4), 256, 0, stream>>>(WX, 0, h*2097152 + 512, 1,
          gW + h*65536, gW + 262144 + h*65536, 256, 256,
          256, 1, WX, 0, h*2097152 + 0, nullptr);
    }
    k_packrk<<<2048, 256, 0, stream>>>(rker, (long)l*1048576, sig, rkReg, rkLds, rkStr);
    for (int h = 0; h < 4; h++){
      // gates z,o: A = pre-conv XN, overwrites z/o cols (conv data now dead)
      k_gemm<<<dim3(64,4), 256, 0, stream>>>(XN, 1024, h*256, 0,
          gW + 524288 + h*65536, gW + 786432 + h*65536, 256, 256,
          256, 1, WX, 0, h*2097152 + 512, nullptr);
    }

    k_recur<<<16, 1024, 0, stream>>>(WX, rkReg, (const uint4*)rkLds, (const uint4*)rkStr,
                                     cell_b, (long)l*4096, gn_w, (long)l*1024, sig, X, 0);

    k_ln<<<8192, 256, 0, stream>>>(X, ln2_w, (long)l*1024, sig, XN, 0);
    k_transpose<<<dim3(84,32), 256, 0, stream>>>(ff_up, (long)l*2752512, sig, fupT, 1024, 2688);
    k_gemm<<<dim3(64,21), 256, 0, stream>>>(XN, 1024, 0, 0, fupT, fupT, 1024, 1<<30,
        1024, 0, U, 2688, 0, nullptr);
    k_act<<<43008, 256, 0, stream>>>(U, E);
    k_transpose<<<dim3(32,42), 256, 0, stream>>>(ff_dn, (long)l*1376256, sig, fdnT, 1344, 1024);
    k_gemm<<<dim3(64,8), 256, 0, stream>>>(E, 1344, 0, 0, fdnT, fdnT, 1344, 1<<30,
        1344, 2, nullptr, 0, 0, X);
  }

  k_ln<<<8192, 256, 0, stream>>>(X, post_w, 0, sig, d_out, 1);
}

// Round 4
// 26617.285 us; speedup vs baseline: 2.4510x; 2.4510x over previous
//
#include <hip/hip_runtime.h>
#include <hip/hip_bf16.h>
#include <hip/hip_fp16.h>
#include <math.h>

// ---------------------------------------------------------------------------
// OfficialXLSTMModel: B=4, S=2048, D=1024, L=4, H=4, DH=256, K=4, UP=1344
// Input dtype (fp32 vs bf16) detected AT RUNTIME from ln1_w's bit pattern.
// Internal compute fp32; residual X fp32; canonical activations bf16.
// Workspace: exactly 128 MiB.
// R8: cut k_recur's per-step instruction volume. R7 showed the asm pin and
//     launch_bounds changed nothing (VGPR=64, dur same) -> weights were
//     already register/AGPR-resident; the real cost is ~70 broadcast
//     ds_read_b128/thread/step (64 of them re-reading the whole fp32 h) +
//     ~500 unfused cvt+fma VALU ops. 70*12cy*16waves ~= 13.4k cy/step
//     matches the measured 17.6k cy/step.
//     Fix: (a) h state packed f16 pairs in LDS (hs16, 512B) and
//     v_dot2_f32_f16 (__builtin_amdgcn_fdot2) -> 1 instr/weight-pair,
//     h reads 64->32 uint4/thread; (b) fast transcendentals in the update
//     (__expf/__logf/__fdividef closed forms for log1p/tanh/sigmoid).
//     Weight partition & packing (R5/R6) unchanged: 64 pairs reg, 24 LDS,
//     40 L2-streamed.
// R5: 1024 thr, thread=(gate,cell), 4 waves/SIMD TLP; araw combine;
//     update+GN on first 4 waves; X+= after barrier 2.
// ---------------------------------------------------------------------------

typedef unsigned int  u32;
typedef unsigned short u16;
typedef __hip_bfloat16 bf16;

typedef short bf16x8 __attribute__((ext_vector_type(8)));   // 8 bf16 MFMA A/B frag
typedef float f32x4  __attribute__((ext_vector_type(4)));   // MFMA C/D frag
typedef _Float16 half2t __attribute__((ext_vector_type(2)));

#define EPSF 1e-5f
#define SIGF32 0x3F800000u

// ---- helpers --------------------------------------------------------------
__device__ __forceinline__ float bfu2f(u16 u){ return __uint_as_float(((u32)u) << 16); }
__device__ __forceinline__ float ldm(const void* p, long i, int f32){
  return f32 ? ((const float*)p)[i] : bfu2f(((const u16*)p)[i]);
}
// f16-pair (w) x f16-pair (h), fp32 accumulate: v_dot2_f32_f16 when available.
__device__ __forceinline__ float qdot(u32 w, u32 hp, float acc){
#if defined(__has_builtin)
#if __has_builtin(__builtin_amdgcn_fdot2)
  return __builtin_amdgcn_fdot2(__builtin_bit_cast(half2t, w),
                                __builtin_bit_cast(half2t, hp), acc, false);
#else
  half2t a = __builtin_bit_cast(half2t, w);
  half2t b = __builtin_bit_cast(half2t, hp);
  acc = fmaf((float)a.x, (float)b.x, acc);
  return fmaf((float)a.y, (float)b.y, acc);
#endif
#else
  half2t a = __builtin_bit_cast(half2t, w);
  half2t b = __builtin_bit_cast(half2t, hp);
  acc = fmaf((float)a.x, (float)b.x, acc);
  return fmaf((float)a.y, (float)b.y, acc);
#endif
}

// ---- canary: signal environmental mismatch through absmax -----------------
__global__ __launch_bounds__(256) void k_canary(const u32* __restrict__ sig,
                                                void* __restrict__ out, int n, float code){
  int f32 = (sig[0] == SIGF32);
  int i = blockIdx.x*256 + threadIdx.x;
  if (i >= n) return;
  float v = (i == 0) ? code : 0.f;
  if (f32) ((float*)out)[i] = v;
  else     ((bf16*)out)[i]  = __float2bfloat16(v);
}

// ---- cast x -> residual X fp32 --------------------------------------------
__global__ __launch_bounds__(256) void k_cast(const void* __restrict__ in,
                                              const u32* __restrict__ sig,
                                              float* __restrict__ out){
  int f32 = (sig[0] == SIGF32);
  long i = (long)blockIdx.x*256 + threadIdx.x;    // < 2097152 (x4 elements)
  if (f32){
    ((float4*)out)[i] = ((const float4*)in)[i];
  } else {
    ushort4 v = ((const ushort4*)in)[i];
    float4 f;
    f.x = bfu2f(v.x); f.y = bfu2f(v.y); f.z = bfu2f(v.z); f.w = bfu2f(v.w);
    ((float4*)out)[i] = f;
  }
}

// ---- generic elementwise convert -> canonical bf16 ------------------------
__global__ __launch_bounds__(256) void k_cvt(const void* __restrict__ src, long off,
                                             const u32* __restrict__ sig,
                                             bf16* __restrict__ dst, int n){
  int f32 = (sig[0] == SIGF32);
  int i = blockIdx.x*256 + threadIdx.x;
  if (i < n) dst[i] = __float2bfloat16(ldm(src, off + i, f32));
}

// ---- LayerNorm over D=1024, fp32 in -> bf16 (or dtype-matched final) out --
__global__ __launch_bounds__(256) void k_ln(const float* __restrict__ X,
                                            const void* __restrict__ w, long woff,
                                            const u32* __restrict__ sig,
                                            void* __restrict__ out, int outf){
  int f32 = (sig[0] == SIGF32);
  int row = blockIdx.x, t = threadIdx.x;
  float4 xv = ((const float4*)(X + (long)row*1024))[t];
  float s1 = xv.x + xv.y + xv.z + xv.w;
  float s2 = xv.x*xv.x + xv.y*xv.y + xv.z*xv.z + xv.w*xv.w;
  #pragma unroll
  for (int off = 32; off >= 1; off >>= 1){ s1 += __shfl_xor(s1, off); s2 += __shfl_xor(s2, off); }
  __shared__ float rb[8];
  if ((t & 63) == 0){ rb[t>>6] = s1; rb[4 + (t>>6)] = s2; }
  __syncthreads();
  s1 = rb[0]+rb[1]+rb[2]+rb[3];
  s2 = rb[4]+rb[5]+rb[6]+rb[7];
  float mu  = s1 * (1.f/1024.f);
  float var = s2 * (1.f/1024.f) - mu*mu;
  float rs  = rsqrtf(fmaxf(var, 0.f) + EPSF);
  float xs[4] = {xv.x, xv.y, xv.z, xv.w};
  #pragma unroll
  for (int j = 0; j < 4; j++){
    float val = (xs[j]-mu)*rs*ldm(w, woff + t*4 + j, f32);
    long oi = (long)row*1024 + t*4 + j;
    if (outf && f32) ((float*)out)[oi] = val;
    else             ((bf16*)out)[oi]  = __float2bfloat16(val);
  }
}

// ---- causal depthwise conv (K=4) + SiLU: XN -> WX z/o column region -------
__global__ __launch_bounds__(256) void k_conv(const bf16* __restrict__ XN,
                                              const void* __restrict__ cw, long cwoff,
                                              const void* __restrict__ cb, long cboff,
                                              const u32* __restrict__ sig,
                                              bf16* __restrict__ WX){
  int f32 = (sig[0] == SIGF32);
  int idx = blockIdx.x*256 + threadIdx.x;        // < 8388608
  int c = idx & 1023;
  int s = (idx >> 10) & 2047;
  int b = idx >> 21;
  float acc = ldm(cb, cboff + c, f32);
  const bf16* xp = XN + idx;
  #pragma unroll
  for (int k = 0; k < 4; k++){
    int sk = s - 3 + k;
    float xv = (sk >= 0) ? (float)xp[(k-3)*1024] : 0.f;
    acc += xv * ldm(cw, cwoff + c*4 + k, f32);
  }
  float sg = 1.f / (1.f + __expf(-acc));
  WX[(long)b*8388608 + (long)(c>>8)*2097152 + (long)s*1024 + 512 + (c & 255)]
      = __float2bfloat16(acc * sg);
}

// ---- pack rker into f16 pairs, three regions ------------------------------
// pair dp in [0,128) covers d = 2dp, 2dp+1.  gc = g*256 + cell (= WX column).
// dp in [0,64):   rkReg[(dp*4 + h)*1024 + gc]                    (VGPR-resident)
// dp in [64,88):  rkLds u32 [(h*6 + k)*1024 + gc]*4 + j, k=(dp-64)>>2, j=(dp-64)&3  (LDS)
// dp in [88,128): rkStr u32 [(h*10 + pg)*1024 + gc]*4 + j, pg=(dp-88)>>2, j=(dp-88)&3 (L2 stream)
__global__ __launch_bounds__(256) void k_packrk(const void* __restrict__ rk, long off,
                                                const u32* __restrict__ sig,
                                                u32* __restrict__ rkReg,
                                                u32* __restrict__ rkLds,
                                                u32* __restrict__ rkStr){
  int f32 = (sig[0] == SIGF32);
  int idx = blockIdx.x*256 + threadIdx.x;        // < 4*1024*128
  if (idx >= 524288) return;
  int dp = idx & 127;
  int gc = (idx >> 7) & 1023;                    // gc = g*256 + cell
  int h  = idx >> 17;
  long p = off + (long)h*262144 + (long)(dp*2)*1024 + gc;
  float a = ldm(rk, p, f32);
  float b = ldm(rk, p + 1024, f32);
  u32 lo = (u32)__builtin_bit_cast(u16, (_Float16)a);
  u32 hi = (u32)__builtin_bit_cast(u16, (_Float16)b);
  u32 v = lo | (hi << 16);
  if (dp < 64){
    rkReg[((long)dp*4 + h)*1024 + gc] = v;
  } else if (dp < 88){
    int k = (dp-64)>>2, j = (dp-64)&3;
    rkLds[((long)(h*6 + k)*1024 + gc)*4 + j] = v;
  } else {
    int pg = (dp-88)>>2, j = (dp-88)&3;
    rkStr[((long)(h*10 + pg)*1024 + gc)*4 + j] = v;
  }
}

// ---- tiled transpose: in[R][C] (fp32/bf16) -> out[C][R] bf16 --------------
__global__ __launch_bounds__(256) void k_transpose(const void* __restrict__ in, long off,
                                                   const u32* __restrict__ sig,
                                                   bf16* __restrict__ out, int R, int C){
  int f32 = (sig[0] == SIGF32);
  __shared__ bf16 tile[32][33];
  int tx = threadIdx.x & 31, ty = threadIdx.x >> 5;
  int r0 = blockIdx.y*32, c0 = blockIdx.x*32;
  #pragma unroll
  for (int i = 0; i < 4; i++)
    tile[ty + i*8][tx] = __float2bfloat16(ldm(in, off + (long)(r0 + ty + i*8)*C + c0 + tx, f32));
  __syncthreads();
  #pragma unroll
  for (int i = 0; i < 4; i++) out[(long)(c0 + ty + i*8)*R + r0 + tx] = tile[tx][ty + i*8];
}

// ---- bf16 MFMA GEMM, 128x128 tile, direct global loads --------------------
__global__ __launch_bounds__(256) void k_gemm(const bf16* __restrict__ A, int lda, int aoff, int agate,
                                              const bf16* __restrict__ B0,
                                              const bf16* __restrict__ B1, int ldb, int nsplit,
                                              int K, int mode,
                                              bf16* __restrict__ outb, int ldo, int woff,
                                              float* __restrict__ resid){
  int lane = threadIdx.x & 63, wv = threadIdx.x >> 6;
  int wrow = wv >> 1, wcol = wv & 1;
  int m15 = lane & 15, q = lane >> 4;
  int mBase = blockIdx.x*128 + wrow*64;
  int nBase = blockIdx.y*128 + wcol*64;

  const bf16* Ap[4]; const bf16* Bp[4];
  #pragma unroll
  for (int i = 0; i < 4; i++){
    int row = mBase + i*16 + m15;
    long abase = agate ? ((long)(row >> 11)*8388608 + (long)(row & 2047)*1024)
                       : ((long)row*lda);
    Ap[i] = A + abase + aoff + q*8;
    int n = nBase + i*16 + m15;
    const bf16* bb = (n < nsplit) ? (B0 + (long)n*ldb) : (B1 + (long)(n - nsplit)*ldb);
    Bp[i] = bb + q*8;
  }
  f32x4 acc[4][4];
  f32x4 zero = {0.f, 0.f, 0.f, 0.f};
  #pragma unroll
  for (int i = 0; i < 4; i++)
    #pragma unroll
    for (int j = 0; j < 4; j++) acc[i][j] = zero;

  for (int k0 = 0; k0 < K; k0 += 32){
    bf16x8 af[4], bfg[4];
    #pragma unroll
    for (int i = 0; i < 4; i++){ af[i]  = *reinterpret_cast<const bf16x8*>(Ap[i]); Ap[i] += 32; }
    #pragma unroll
    for (int i = 0; i < 4; i++){ bfg[i] = *reinterpret_cast<const bf16x8*>(Bp[i]); Bp[i] += 32; }
    #pragma unroll
    for (int i = 0; i < 4; i++)
      #pragma unroll
      for (int j = 0; j < 4; j++)
        acc[i][j] = __builtin_amdgcn_mfma_f32_16x16x32_bf16(af[i], bfg[j], acc[i][j], 0, 0, 0);
  }

  #pragma unroll
  for (int i = 0; i < 4; i++){
    #pragma unroll
    for (int j = 0; j < 4; j++){
      #pragma unroll
      for (int r = 0; r < 4; r++){
        int row = mBase + i*16 + q*4 + r;       // C/D layout: col=lane&15, row=quad*4+reg
        int col = nBase + j*16 + m15;
        float v = acc[i][j][r];
        if (mode == 0){
          outb[(long)row*ldo + col] = __float2bfloat16(v);
        } else if (mode == 1){
          outb[(long)(row >> 11)*8388608 + (long)(row & 2047)*1024 + woff + col] = __float2bfloat16(v);
        } else {
          resid[(long)row*1024 + col] += v;
        }
      }
    }
  }
}

// ---- GEGLU activation: U[8192][2688] -> E[8192][1344] ---------------------
__global__ __launch_bounds__(256) void k_act(const bf16* __restrict__ U, bf16* __restrict__ E){
  int idx = blockIdx.x*256 + threadIdx.x;        // < 8192*1344
  int row = idx / 1344;
  int j   = idx - row*1344;
  float g = (float)U[(long)row*2688 + j];
  float v = (float)U[(long)row*2688 + 1344 + j];
  float ge = 0.5f * g * (1.f + erff(g * 0.70710678118654752f));
  E[idx] = __float2bfloat16(ge * v);
}

// ---- sLSTM recurrence + fused GroupNorm + residual add --------------------
// 16 workgroups = (b,h); 1024 threads; thread tid = (gate g = tid>>8, cell = tid&255).
// h state kept as PACKED F16 PAIRS in LDS (hs16, 512 B); every weight pair
// multiplies via v_dot2_f32_f16 (1 instr) against a broadcast h-pair.
// Per step: dots -> araw[tid]; B1; first 4 waves: cell update (fast
// transcendentals) + hs16 write + GN reduce; B2; GN+residual overlaps next dots.
__global__ __launch_bounds__(1024, 4) void k_recur(const bf16* __restrict__ WX,  // [16][2048][1024]
                                                const u32*  __restrict__ rkReg,  // [64 dp][4 h][1024 gc]
                                                const uint4* __restrict__ rkLdsG,// [4 h][6 k][1024 gc]
                                                const uint4* __restrict__ rkStrG,// [4 h][10 pg][1024 gc]
                                                const void* __restrict__ cb, long cboff,
                                                const void* __restrict__ gnw, long gnoff,
                                                const u32*  __restrict__ sig,
                                                float* __restrict__ X,
                                                int szero){
  int f32 = (sig[0] == SIGF32);
  int bh = blockIdx.x;
  int b = bh >> 2, h = bh & 3;
  int tid = threadIdx.x;
  int cell = tid & 255;

  // resident weights: 64 f16-pairs (d = 0..127)
  u32 wreg[64];
  {
    const u32* rg = rkReg + h*1024 + tid;
    #pragma unroll
    for (int i = 0; i < 64; i++) wreg[i] = rg[i*4096];
  }
  #pragma unroll
  for (int i = 0; i < 64; i++) asm volatile("" : "+v"(wreg[i]));

  __shared__ __align__(16) uint4 wlds[6144];     // 96 KB: pairs d=128..175, [k][tid]
  __shared__ __align__(16) float araw[1024];     // raw gate pre-activations
  __shared__ __align__(16) u16 hs16[256];        // h state, packed f16
  __shared__ float rbuf[8];
  {
    const uint4* srcL = rkLdsG + h*6144;
    #pragma unroll
    for (int k = 0; k < 6; k++) wlds[k*1024 + tid] = srcL[k*1024 + tid];
  }

  // L2-stream base: pairs d=176..255, 10 coalesced uint4 per thread per step
  const uint4* st = rkStrG + h*10240 + tid;

  float bias = ldm(cb, cboff + h*1024 + tid, f32);
  float gw   = ldm(gnw, gnoff + h*256 + cell, f32);

  if (tid < 256) hs16[tid] = 0;
  __syncthreads();

  float c = 0.f, n = 0.f, m = 0.f;               // live in first 4 waves only
  const u16* wxu = (const u16*)(WX + (long)bh*2097152) + tid;
  float* Xp = X + (long)b*2097152 + h*256 + cell;

  u16 wxc = wxu[0];
  for (int s = 0; s < 2048; s++){
    u16 wxn = wxu[(s < 2047) ? 1024 : 0];        // prefetch next step's input
    int off = s * szero;                         // runtime 0: defeats LICM on
    const uint4* hq = (const uint4*)hs16;        // LDS + L2 weight loads

    float acc = bias + bfu2f(wxc);
    #pragma unroll
    for (int j2 = 0; j2 < 16; j2++){             // pairs 0..63 (registers)
      uint4 hv = hq[j2];
      acc = qdot(wreg[4*j2+0], hv.x, acc);
      acc = qdot(wreg[4*j2+1], hv.y, acc);
      acc = qdot(wreg[4*j2+2], hv.z, acc);
      acc = qdot(wreg[4*j2+3], hv.w, acc);
    }
    #pragma unroll
    for (int k = 0; k < 6; k++){                 // pairs 64..87 (LDS)
      uint4 q = wlds[k*1024 + tid + off];
      uint4 hv = hq[16+k];
      acc = qdot(q.x, hv.x, acc); acc = qdot(q.y, hv.y, acc);
      acc = qdot(q.z, hv.z, acc); acc = qdot(q.w, hv.w, acc);
    }
    #pragma unroll
    for (int pg = 0; pg < 10; pg++){             // pairs 88..127 (L2 stream)
      uint4 q = st[pg*1024 + off];
      uint4 hv = hq[22+pg];
      acc = qdot(q.x, hv.x, acc); acc = qdot(q.y, hv.y, acc);
      acc = qdot(q.z, hv.z, acc); acc = qdot(q.w, hv.w, acc);
    }
    araw[tid] = acc;
    __syncthreads();                             // B1: araw ready; old hs16 consumed

    float y = 0.f;
    if (tid < 256){
      float a0 = araw[cell], a1 = araw[256+cell], a2 = araw[512+cell], a3 = araw[768+cell];
      // log-sigmoid: min(a1,0) - log(1 + exp(-|a1|))   (__logf arg in (1,2])
      float e1   = __expf(-fabsf(a1));
      float lsig = fminf(a1, 0.f) - __logf(1.f + e1);
      float lfm  = m + lsig;
      float mn   = fmaxf(a0, lfm);
      float ig   = __expf(a0 - mn);
      float fg   = __expf(lfm - mn);
      // tanh: sign(a2) * (1 - e)/(1 + e), e = exp(-2|a2|) in (0,1]
      float t2   = __expf(-2.f*fabsf(a2));
      float th   = __builtin_copysignf(__fdividef(1.f - t2, 1.f + t2), a2);
      float cn   = fg*c + ig*th;
      float nn   = fg*n + ig;
      float sg   = __fdividef(1.f, 1.f + __expf(-a3));
      float hn   = sg * __fdividef(cn, nn);
      c = cn; n = nn; m = mn;
      hs16[cell] = __builtin_bit_cast(u16, (_Float16)hn);  // safe: old hs16 dead past B1
      float r1 = hn, r2 = hn*hn;
      #pragma unroll
      for (int o2 = 32; o2 >= 1; o2 >>= 1){ r1 += __shfl_xor(r1, o2); r2 += __shfl_xor(r2, o2); }
      if ((tid & 63) == 0){ rbuf[tid>>6] = r1; rbuf[4 + (tid>>6)] = r2; }
      y = hn;
    }
    __syncthreads();                             // B2: hs16 + rbuf ready

    if (tid < 256){                              // GN + residual overlap next dots
      float S1 = rbuf[0]+rbuf[1]+rbuf[2]+rbuf[3];
      float S2 = rbuf[4]+rbuf[5]+rbuf[6]+rbuf[7];
      float mu  = S1 * (1.f/256.f);
      float var = S2 * (1.f/256.f) - mu*mu;
      *Xp += (y - mu) * rsqrtf(fmaxf(var, 0.f) + EPSF) * gw;
    }
    Xp += 1024;
    wxu += 1024;
    wxc = wxn;
  }
}

// ---------------------------------------------------------------------------
extern "C" void kernel_launch(void* const* d_in, const int* in_sizes, int n_in,
                              void* d_out, int out_size, void* d_ws, size_t ws_size,
                              hipStream_t stream){
  const void* x_in   = d_in[0];
  const void* ln1_w  = d_in[1];
  const void* conv_w = d_in[2];
  const void* conv_b = d_in[3];
  const void* wi     = d_in[4];
  const void* wf     = d_in[5];
  const void* wz     = d_in[6];
  const void* wo     = d_in[7];
  const void* rker   = d_in[8];
  const void* cell_b = d_in[9];
  const void* gn_w   = d_in[10];
  const void* ln2_w  = d_in[11];
  const void* ff_up  = d_in[12];
  const void* ff_dn  = d_in[13];
  const void* post_w = d_in[14];
  const u32* sig = (const u32*)ln1_w;

  if (ws_size < 134217728ULL){
    k_canary<<<(out_size+255)/256, 256, 0, stream>>>(sig, d_out, out_size, 4000.f);
    return;
  }
  if (n_in < 15 || in_sizes[0] != 8388608 || in_sizes[8] != 4194304 ||
      in_sizes[12] != 11010048 || out_size != 8388608){
    k_canary<<<(out_size+255)/256, 256, 0, stream>>>(sig, d_out, out_size, 8000.f);
    return;
  }

  char* ws = (char*)d_ws;
  // layout (exactly 128 MiB):
  //   [0,32M)    X    fp32 residual
  //   [32,48M)   XN   bf16 LN output
  //   [48,64M)   scratch: rkReg 1M | rkLds 384K | rkStr 640K | gW 2M | fupT 5.25M | fdnT 2.63M
  //   [64,128M)  WX bf16 [4 b][4 h][2048 s][1024]; conv output lives in its
  //              z/o cols until side-1 gemms; U(44M)+E(21M) alias it in FFN.
  float* X    = (float*)(ws + 0);
  bf16*  XN   = (bf16*) (ws + 33554432);
  u32*   rkReg= (u32*)  (ws + 50331648);
  u32*   rkLds= (u32*)  (ws + 50331648 + 1048576);
  u32*   rkStr= (u32*)  (ws + 50331648 + 1441792);
  bf16*  gW   = (bf16*) (ws + 50331648 + 2097152);
  bf16*  fupT = (bf16*) (ws + 50331648 + 4194304);
  bf16*  fdnT = (bf16*) (ws + 50331648 + 9699328);
  bf16*  WX   = (bf16*) (ws + 67108864);
  bf16*  U    = WX;
  bf16*  E    = (bf16*) (ws + 67108864 + 44040192);

  k_cast<<<8192, 256, 0, stream>>>(x_in, sig, X);

  for (int l = 0; l < 4; l++){
    k_ln<<<8192, 256, 0, stream>>>(X, ln1_w, (long)l*1024, sig, XN, 0);
    k_conv<<<32768, 256, 0, stream>>>(XN, conv_w, (long)l*4096, conv_b, (long)l*1024, sig, WX);

    // canonical bf16 gate weights for this layer
    k_cvt<<<1024, 256, 0, stream>>>(wi, (long)l*262144, sig, gW +      0, 262144);
    k_cvt<<<1024, 256, 0, stream>>>(wf, (long)l*262144, sig, gW + 262144, 262144);
    k_cvt<<<1024, 256, 0, stream>>>(wz, (long)l*262144, sig, gW + 524288, 262144);
    k_cvt<<<1024, 256, 0, stream>>>(wo, (long)l*262144, sig, gW + 786432, 262144);

    for (int h = 0; h < 4; h++){
      // gates i,f: A = conv output (in WX z/o cols), writes i/f cols
      k_gemm<<<dim3(64,4), 256, 0, stream>>>(WX, 0, h*2097152 + 512, 1,
          gW + h*65536, gW + 262144 + h*65536, 256, 256,
          256, 1, WX, 0, h*2097152 + 0, nullptr);
    }
    k_packrk<<<2048, 256, 0, stream>>>(rker, (long)l*1048576, sig, rkReg, rkLds, rkStr);
    for (int h = 0; h < 4; h++){
      // gates z,o: A = pre-conv XN, overwrites z/o cols (conv data now dead)
      k_gemm<<<dim3(64,4), 256, 0, stream>>>(XN, 1024, h*256, 0,
          gW + 524288 + h*65536, gW + 786432 + h*65536, 256, 256,
          256, 1, WX, 0, h*2097152 + 512, nullptr);
    }

    k_recur<<<16, 1024, 0, stream>>>(WX, rkReg, (const uint4*)rkLds, (const uint4*)rkStr,
                                     cell_b, (long)l*4096, gn_w, (long)l*1024, sig, X, 0);

    k_ln<<<8192, 256, 0, stream>>>(X, ln2_w, (long)l*1024, sig, XN, 0);
    k_transpose<<<dim3(84,32), 256, 0, stream>>>(ff_up, (long)l*2752512, sig, fupT, 1024, 2688);
    k_gemm<<<dim3(64,21), 256, 0, stream>>>(XN, 1024, 0, 0, fupT, fupT, 1024, 1<<30,
        1024, 0, U, 2688, 0, nullptr);
    k_act<<<43008, 256, 0, stream>>>(U, E);
    k_transpose<<<dim3(32,42), 256, 0, stream>>>(ff_dn, (long)l*1376256, sig, fdnT, 1344, 1024);
    k_gemm<<<dim3(64,8), 256, 0, stream>>>(E, 1344, 0, 0, fdnT, fdnT, 1344, 1<<30,
        1344, 2, nullptr, 0, 0, X);
  }

  k_ln<<<8192, 256, 0, stream>>>(X, post_w, 0, sig, d_out, 1);
}